// Round 4
// baseline (678.058 us; speedup 1.0000x reference)
//
#include <hip/hip_runtime.h>

// ---------------------------------------------------------------------------
// NAMTuring forward, MI355X.
//  K0 convert -> K1 input GEMMs (xproj in lstm-permuted layout) -> K2 biLSTM
//  scan (1 barrier/step, coalesced xproj, LDS-dump hidden) -> K3 action GEMM
//  -> K4 pos scan (fused softmax, 1 wave, shfl) -> K5 tape scan -> K6 out GEMM
// S=256 B=64 IN=128 HID=128 NT=2 DIM=64 LH=64 TAPELEN=128
// ---------------------------------------------------------------------------

typedef unsigned short u16;
typedef __attribute__((ext_vector_type(8))) __bf16 bf16x8;
typedef __attribute__((ext_vector_type(4))) float f32x4;

__device__ __forceinline__ u16 f2bf(float x) {
  unsigned u = __builtin_bit_cast(unsigned, x);
  u += 0x7fffu + ((u >> 16) & 1u);
  return (u16)(u >> 16);
}
__device__ __forceinline__ float sigm_f(float x) { return 1.f / (1.f + __expf(-x)); }
__device__ __forceinline__ float tanh_f(float x) { return 1.f - 2.f / (__expf(2.f * x) + 1.f); }

// ---------------- K0: f32 -> bf16 conversions (one launch) -----------------
struct ConvArgs {
  const float* src[8];
  u16* dst[8];
  int off[9];
};

__global__ __launch_bounds__(256) void k_convert(ConvArgs a) {
  int i = blockIdx.x * 256 + threadIdx.x;
  if (i < 524288) {            // inputs: 2097152 f32 as float4
    float4 vv = ((const float4*)a.src[0])[i];
    uint2 o;
    o.x = (unsigned)f2bf(vv.x) | ((unsigned)f2bf(vv.y) << 16);
    o.y = (unsigned)f2bf(vv.z) | ((unsigned)f2bf(vv.w) << 16);
    ((uint2*)a.dst[0])[i] = o;
  } else if (i < 657408) {     // weights: scalar tail
    int ii = i - 524288 + 2097152;
    int s = 1;
#pragma unroll
    for (int k = 2; k < 8; ++k) s += (ii >= a.off[k]);
    int j = ii - a.off[s];
    a.dst[s][j] = f2bf(a.src[s][j]);
  }
}

// ------------- per-wave 16x16 MFMA tile, C = A @ W^T + bias, K=128 ----------
__device__ __forceinline__ void gemm_tile(const u16* A, const u16* W,
                                          const float* b1, float* C,
                                          int mt, int nt, int N, int lane) {
  const int rc = lane & 15;
  const int kq = lane >> 4;
  f32x4 acc = {0.f, 0.f, 0.f, 0.f};
#pragma unroll
  for (int kc = 0; kc < 4; ++kc) {
    bf16x8 av = *(const bf16x8*)(A + (size_t)(mt * 16 + rc) * 128 + kc * 32 + kq * 8);
    bf16x8 wv = *(const bf16x8*)(W + (size_t)(nt * 16 + rc) * 128 + kc * 32 + kq * 8);
    acc = __builtin_amdgcn_mfma_f32_16x16x32_bf16(av, wv, acc, 0, 0, 0);
  }
  const int n = nt * 16 + rc;
  float bias = b1[n];
  const int m0 = mt * 16 + kq * 4;
#pragma unroll
  for (int j = 0; j < 4; ++j) C[(size_t)(m0 + j) * N + n] = acc[j] + bias;
}

// xproj variant: writes to the k_lstm-permuted layout (contiguous float4).
// dst index = (((s*4+cb)*4+kq2)*64 + v2*16+cl2)*16 + gt*4 + j
__device__ __forceinline__ void gemm_tile_xp(const u16* A, const u16* W,
                                             const float* b1, const float* b2,
                                             float* X, int mt, int nt, int lane) {
  const int rc = lane & 15;
  const int kq = lane >> 4;
  f32x4 acc = {0.f, 0.f, 0.f, 0.f};
#pragma unroll
  for (int kc = 0; kc < 4; ++kc) {
    bf16x8 av = *(const bf16x8*)(A + (size_t)(mt * 16 + rc) * 128 + kc * 32 + kq * 8);
    bf16x8 wv = *(const bf16x8*)(W + (size_t)(nt * 16 + rc) * 128 + kc * 32 + kq * 8);
    acc = __builtin_amdgcn_mfma_f32_16x16x32_bf16(av, wv, acc, 0, 0, 0);
  }
  const int n = nt * 16 + rc;
  const float bias = b1[n] + b2[n];
  const int m0 = mt * 16 + kq * 4;
  const int s = m0 >> 6, brow0 = m0 & 63;
  const int cb = brow0 >> 4, kq2 = (brow0 & 15) >> 2;
  const int gt = n >> 6, v2 = (n >> 4) & 3, cl2 = n & 15;
  unsigned off = (((unsigned)(s * 4 + cb) * 4 + kq2) * 64 + v2 * 16 + cl2) * 16 + gt * 4;
  f32x4 o;
#pragma unroll
  for (int j = 0; j < 4; ++j) o[j] = acc[j] + bias;
  *(f32x4*)(X + off) = o;
}

// ---------------- K1: xproj_f, xproj_r, values in one launch ----------------
__global__ __launch_bounds__(256) void k_gemm_in(
    const u16* __restrict__ Abf, const u16* __restrict__ Wf,
    const u16* __restrict__ Wr, const u16* __restrict__ Wv,
    const float* bihf, const float* bhhf, const float* bihr, const float* bhhr,
    const float* bval, float* xf, float* xr, float* val) {
  int lane = threadIdx.x & 63;
  int wid = blockIdx.x * 4 + (threadIdx.x >> 6);   // 0..40959
  if (wid < 16384) {
    gemm_tile_xp(Abf, Wf, bihf, bhhf, xf, wid >> 4, wid & 15, lane);
  } else if (wid < 32768) {
    int w2 = wid - 16384;
    gemm_tile_xp(Abf, Wr, bihr, bhhr, xr, w2 >> 4, w2 & 15, lane);
  } else {
    int w2 = wid - 32768;
    gemm_tile(Abf, Wv, bval, val, w2 >> 3, w2 & 7, 128, lane);
  }
}

// ---------------- K3: action pre-act GEMM: hidden_bf @ W_act^T + b ----------
__global__ __launch_bounds__(256) void k_gemm_act(const u16* __restrict__ A,
                                                  const u16* __restrict__ W,
                                                  const float* b1, float* C) {
  int lane = threadIdx.x & 63;
  int wid = blockIdx.x * 4 + (threadIdx.x >> 6);   // 0..2047 M-tiles, N=16
  gemm_tile(A, W, b1, C, wid, 0, 16, lane);
}

// ---------------- K6: outputs = readouts @ W_out^T + b_out ------------------
__global__ __launch_bounds__(256) void k_gemm_out(const u16* __restrict__ A,
                                                  const u16* __restrict__ W,
                                                  const float* b1, float* C) {
  int lane = threadIdx.x & 63;
  int wid = blockIdx.x * 4 + (threadIdx.x >> 6);   // 0..8191
  gemm_tile(A, W, b1, C, wid >> 3, wid & 7, 128, lane);
}

// ---------------- K2: bidirectional LSTM scan -------------------------------
// 8 blocks (dir + 2*chunk16) x 4 waves. Wave v owns cols [16v,16v+16) of each
// gate. Coalesced xproj (permuted layout, 4x dwordx4, +const offset).
// hidden written via LDS dump next step (coalesced dwordx2). 1 barrier/step.
__global__ __launch_bounds__(256, 1) void k_lstm(
    const u16* __restrict__ Whhf, const u16* __restrict__ Whhr,
    const float* __restrict__ xpf, const float* __restrict__ xpr,
    u16* __restrict__ hidden_bf /* [S][B][128] bf16 */) {
  const int tid = threadIdx.x;
  const int lane = tid & 63;
  const int v = __builtin_amdgcn_readfirstlane(tid >> 6);
  const int dir = blockIdx.x & 1;
  const int cb = blockIdx.x >> 1;
  const int b_base = cb * 16;
  const u16* Whh = dir ? Whhr : Whhf;
  const float* xp = dir ? xpr : xpf;

  __shared__ u16 h_lds[2][1024];   // [buf][16 rows][64 cols] bf16, XOR-swizzled
  for (int i = tid; i < 1024; i += 256) h_lds[0][i] = 0;

  const int cl = lane & 15;
  const int kq = lane >> 4;
  const int nbase = v * 16 + cl;

  // Whh fragments (rows = gate gt*64+nbase, K=64 over 2 chunks)
  bf16x8 wf[4][2];
#pragma unroll
  for (int gt = 0; gt < 4; ++gt)
#pragma unroll
    for (int kc = 0; kc < 2; ++kc)
      wf[gt][kc] = *(const bf16x8*)(Whh + (size_t)(gt * 64 + nbase) * 64 + kc * 32 + kq * 8);

  float c4[4] = {0.f, 0.f, 0.f, 0.f};

  // xproj offsets (permuted layout): off(s) = (s*4+cb)*4096 + kq*1024 + nbase*16
  const unsigned tconst = (unsigned)kq * 1024u + (unsigned)nbase * 16u;
  const int s0i = dir ? 255 : 0, s1i = dir ? 254 : 1;
  unsigned x0off = (unsigned)(s0i * 4 + cb) * 4096u + tconst;
  unsigned x1off = (unsigned)(s1i * 4 + cb) * 4096u + tconst;
  const unsigned xstride = dir ? (unsigned)(-32768) : 32768u;

  // hidden dump: thread handles 8B; row=tid>>4, colbytes=(tid&15)*8
  const unsigned dsrc = ((unsigned)tid * 8u) ^ ((((unsigned)tid >> 4) & 7u) << 4);
  unsigned hoff = (unsigned)(dir ? 255 : 0) * 16384u +
                  (unsigned)(b_base + (tid >> 4)) * 256u + (unsigned)dir * 128u +
                  ((unsigned)tid & 15u) * 8u;
  const unsigned hstride = dir ? (unsigned)(-16384) : 16384u;

  // LDS write addrs (4 rows), per buffer parity
  unsigned aw[4];
#pragma unroll
  for (int j = 0; j < 4; ++j) {
    unsigned r = (unsigned)(kq * 4 + j);
    aw[j] = (r * 128u + (unsigned)nbase * 2u) ^ ((r & 7u) << 4);
  }
  unsigned ar[2];
#pragma unroll
  for (int kc = 0; kc < 2; ++kc)
    ar[kc] = ((unsigned)(cl * 128 + kc * 64 + kq * 16)) ^ (((unsigned)cl & 7u) << 4);

  f32x4 x0[4], x1[4];
#define LOADX(X, OFF)                                                          \
  {                                                                            \
    const f32x4* p_ = (const f32x4*)(xp + OFF);                                \
    X[0] = p_[0]; X[1] = p_[1]; X[2] = p_[2]; X[3] = p_[3];                    \
  }
  LOADX(x0, x0off);
  LOADX(x1, x1off);
  x0off += xstride; x1off += xstride;

#define LSTM_STEP(XB, XOFF, IT, PAR)                                           \
  {                                                                            \
    const int it_ = (IT);                                                      \
    __syncthreads();                                                           \
    if (it_ > 0) { /* dump h(s_prev) from buf[PAR] */                          \
      uint2 hv2 = *(const uint2*)((const char*)h_lds + ((PAR) << 11) + dsrc);  \
      *(uint2*)((char*)hidden_bf + hoff) = hv2;                                \
      hoff += hstride;                                                         \
    }                                                                          \
    bf16x8 af[2];                                                              \
    _Pragma("unroll") for (int kc = 0; kc < 2; ++kc)                           \
      af[kc] = *(const bf16x8*)((const char*)h_lds + ((PAR) << 11) + ar[kc]);  \
    f32x4 acc[4];                                                              \
    _Pragma("unroll") for (int gt = 0; gt < 4; ++gt)                           \
      acc[gt] = __builtin_amdgcn_mfma_f32_16x16x32_bf16(af[0], wf[gt][0],      \
                                                        XB[gt], 0, 0, 0);      \
    if (it_ + 2 < 256) { LOADX(XB, XOFF); XOFF += xstride; }                   \
    _Pragma("unroll") for (int gt = 0; gt < 4; ++gt)                           \
      acc[gt] = __builtin_amdgcn_mfma_f32_16x16x32_bf16(af[1], wf[gt][1],      \
                                                        acc[gt], 0, 0, 0);     \
    float hh[4];                                                               \
    _Pragma("unroll") for (int j = 0; j < 4; ++j) {                            \
      float gi = sigm_f(acc[0][j]);                                            \
      float gf = sigm_f(acc[1][j]);                                            \
      float gg = tanh_f(acc[2][j]);                                            \
      float go = sigm_f(acc[3][j]);                                            \
      float cc = gf * c4[j] + gi * gg;                                         \
      c4[j] = cc;                                                              \
      hh[j] = go * tanh_f(cc);                                                 \
    }                                                                          \
    unsigned p01, p23;                                                         \
    asm("v_cvt_pk_bf16_f32 %0, %1, %2" : "=v"(p01) : "v"(hh[0]), "v"(hh[1]));  \
    asm("v_cvt_pk_bf16_f32 %0, %1, %2" : "=v"(p23) : "v"(hh[2]), "v"(hh[3]));  \
    char* hw = (char*)h_lds + ((1 - (PAR)) << 11);                             \
    *(u16*)(hw + aw[0]) = (u16)p01;                                            \
    *(u16*)(hw + aw[1]) = (u16)(p01 >> 16);                                    \
    *(u16*)(hw + aw[2]) = (u16)p23;                                            \
    *(u16*)(hw + aw[3]) = (u16)(p23 >> 16);                                    \
  }

  for (int it2 = 0; it2 < 256; it2 += 2) {
    LSTM_STEP(x0, x0off, it2, 0);
    LSTM_STEP(x1, x1off, it2 + 1, 1);
  }
#undef LSTM_STEP
#undef LOADX

  __syncthreads();   // final h in buf0
  {
    uint2 hv2 = *(const uint2*)((const char*)h_lds + dsrc);
    *(uint2*)((char*)hidden_bf + hoff) = hv2;
  }
}

// ---------------- K4: position scan (fused softmax), 1 wave/chain -----------
__global__ __launch_bounds__(64) void k_pos(const float* __restrict__ raw,
                                            u16* __restrict__ wcoef, u16* __restrict__ rcoef,
                                            float* rw1arr, float* out_rpos, float* out_wpos) {
  const int bt = blockIdx.x;
  const int l = threadIdx.x;
  const int b = bt >> 1, tt = bt & 1;
  const float* abase = raw + (size_t)b * 16 + tt * 8;   // step stride 1024
  float4 d0 = *(const float4*)abase;
  float4 d1 = *(const float4*)(abase + 4);
  float rpe = (l == 0) ? 1.f : 0.f, rpo = 0.f;
  float wpe = rpe, wpo = 0.f;
  unsigned* wcu = (unsigned*)wcoef;
  unsigned* rcu = (unsigned*)rcoef;
  for (int s = 0; s < 256; ++s) {
    float m1 = fmaxf(fmaxf(d0.x, d0.y), d0.z);
    float e0 = __expf(d0.x - m1), e1 = __expf(d0.y - m1), e2 = __expf(d0.z - m1);
    float i1 = 1.f / (e0 + e1 + e2);
    float m2 = fmaxf(fmaxf(d0.w, d1.x), d1.y);
    float f0 = __expf(d0.w - m2), f1 = __expf(d1.x - m2), f2 = __expf(d1.y - m2);
    float i2 = 1.f / (f0 + f1 + f2);
    float rd0 = e0 * i1, rd1 = e1 * i1, rd2 = e2 * i1;
    float wd0 = f0 * i2, wd1 = f1 * i2, wd2 = f2 * i2;
    float rw0 = sigm_f(d1.z), rw1 = sigm_f(d1.w);
    if (s + 1 < 256) {
      const float* an = abase + (size_t)(s + 1) * 1024;
      d0 = *(const float4*)an;
      d1 = *(const float4*)(an + 4);
    }
    size_t ci = ((size_t)s * 128 + bt) * 64 + l;
    wcu[ci] = (unsigned)f2bf(wpe) | ((unsigned)f2bf(wpo) << 16);
    rcu[ci] = (unsigned)f2bf(rpe * rw0) | ((unsigned)f2bf(rpo * rw0) << 16);
    if (l == 0) rw1arr[s * 128 + bt] = rw1;
    float up_odd = __shfl(rpo, (l + 63) & 63);
    float dn_even = __shfl(rpe, (l + 1) & 63);
    float n_e = up_odd, n_o = rpe;
    float p_e = rpo, p_o = dn_even;
    wpe = p_e * wd0 + wpe * wd1 + n_e * wd2;
    wpo = p_o * wd0 + wpo * wd1 + n_o * wd2;
    rpe = p_e * rd0 + rpe * rd1 + n_e * rd2;
    rpo = p_o * rd0 + rpo * rd1 + n_o * rd2;
  }
  out_rpos[((size_t)(2 * l) * 64 + b) * 2 + tt] = rpe;
  out_rpos[((size_t)(2 * l + 1) * 64 + b) * 2 + tt] = rpo;
  out_wpos[((size_t)(2 * l) * 64 + b) * 2 + tt] = wpe;
  out_wpos[((size_t)(2 * l + 1) * 64 + b) * 2 + tt] = wpo;
}

// ---------------- K5: tape scan — 1 barrier/step, scalar coefs --------------
__global__ __launch_bounds__(256, 1) void k_tape(
    const float* __restrict__ values, const u16* __restrict__ wcoef,
    const u16* __restrict__ rcoef, const float* __restrict__ rw1arr,
    u16* __restrict__ readouts, float* __restrict__ out_tape) {
  const int bt = blockIdx.x;
  const int b = bt >> 1, t = bt & 1;
  const int tid = threadIdx.x;
  const int c = tid & 63;
  const int g = __builtin_amdgcn_readfirstlane(tid >> 6);
  __shared__ float lds_po[2][256];
  __shared__ float lds_pr[2][256];
  float tape[32];
#pragma unroll
  for (int j = 0; j < 32; ++j) tape[j] = 0.f;

  const unsigned* wcu = (const unsigned*)wcoef;
  const unsigned* rcu = (const unsigned*)rcoef;
  const size_t cbase = (size_t)bt * 64 + g * 16;
  const size_t vbase = (size_t)b * 128 + t * 64 + c;
  unsigned wA[16], rA[16], wB[16], rB[16];
  float rwA, rwB, vA, vB;
#pragma unroll
  for (int q = 0; q < 16; ++q) { wA[q] = wcu[cbase + q]; rA[q] = rcu[cbase + q]; }
  rwA = rw1arr[bt]; vA = values[vbase];
  {
    size_t nb = cbase + 8192;
#pragma unroll
    for (int q = 0; q < 16; ++q) { wB[q] = wcu[nb + q]; rB[q] = rcu[nb + q]; }
    rwB = rw1arr[128 + bt]; vB = values[8192 + vbase];
  }

#define BCF(u) __builtin_bit_cast(float, (u))
#define TSTEP(CW, CR, CRW, CV, S)                                              \
  {                                                                            \
    const int s_ = (S);                                                        \
    float rwc = CRW, vcl = CV;                                                 \
    float po_[4] = {0.f, 0.f, 0.f, 0.f};                                       \
    _Pragma("unroll") for (int q = 0; q < 16; ++q) {                           \
      unsigned cw = (unsigned)__builtin_amdgcn_readfirstlane(CW[q]);           \
      po_[q & 3] += tape[2 * q] * BCF(cw << 16);                               \
      po_[q & 3] += tape[2 * q + 1] * BCF(cw & 0xffff0000u);                   \
    }                                                                          \
    if (s_ + 2 < 256) {                                                        \
      size_t nb = cbase + (size_t)(s_ + 2) * 8192;                             \
      _Pragma("unroll") for (int q = 0; q < 16; ++q) {                         \
        CW[q] = wcu[nb + q]; CR[q] = rcu[nb + q]; }                            \
      CRW = rw1arr[(s_ + 2) * 128 + bt];                                       \
      CV = values[(size_t)(s_ + 2) * 8192 + vbase];                            \
    }                                                                          \
    lds_po[s_ & 1][(g << 6) + c] = (po_[0] + po_[1]) + (po_[2] + po_[3]);      \
    __syncthreads();                                                           \
    if (g == 1 && s_ > 0) {                                                    \
      const float* pp = lds_pr[(s_ - 1) & 1];                                  \
      float ro = (pp[c] + pp[64 + c]) + (pp[128 + c] + pp[192 + c]);           \
      readouts[((size_t)(s_ - 1) * 64 + b) * 128 + t * 64 + c] = f2bf(ro);     \
    }                                                                          \
    const float* qq = lds_po[s_ & 1];                                          \
    float oldv = (qq[c] + qq[64 + c]) + (qq[128 + c] + qq[192 + c]);           \
    float dsc = rwc * (vcl - oldv);                                            \
    float pr_[4] = {0.f, 0.f, 0.f, 0.f};                                       \
    _Pragma("unroll") for (int q = 0; q < 16; ++q) {                           \
      unsigned cw = (unsigned)__builtin_amdgcn_readfirstlane(CW[q]);           \
      unsigned cr = (unsigned)__builtin_amdgcn_readfirstlane(CR[q]);           \
      tape[2 * q] += BCF(cw << 16) * dsc;                                      \
      pr_[q & 3] += tape[2 * q] * BCF(cr << 16);                               \
      tape[2 * q + 1] += BCF(cw & 0xffff0000u) * dsc;                          \
      pr_[q & 3] += tape[2 * q + 1] * BCF(cr & 0xffff0000u);                   \
    }                                                                          \
    lds_pr[s_ & 1][(g << 6) + c] = (pr_[0] + pr_[1]) + (pr_[2] + pr_[3]);      \
  }

  for (int s = 0; s < 256; s += 2) {
    TSTEP(wA, rA, rwA, vA, s);
    TSTEP(wB, rB, rwB, vB, s + 1);
  }
#undef TSTEP
#undef BCF
  __syncthreads();
  if (g == 1) {
    const float* pp = lds_pr[1];
    float ro = (pp[c] + pp[64 + c]) + (pp[128 + c] + pp[192 + c]);
    readouts[((size_t)255 * 64 + b) * 128 + t * 64 + c] = f2bf(ro);
  }
#pragma unroll
  for (int j = 0; j < 32; ++j) {
    int l = (g << 5) + j;
    out_tape[((size_t)(l * 64 + b) * 2 + t) * 64 + c] = tape[j];
  }
}

// NOTE: prefetch CW/CR are loaded AFTER the first readfirstlane pass uses the
// old values (po pass), and the second pass (update/pr) uses the NEW values?
// No — second pass must use the CURRENT step's coefs. See fix below in launch:
// the prefetch in TSTEP overwrites CW/CR between the po pass and the update
// pass, which would be WRONG. To keep it correct we snapshot the needed
// scalars in the first pass. -- Handled: see k_tape2 below (actually used).

__global__ __launch_bounds__(256, 1) void k_tape2(
    const float* __restrict__ values, const u16* __restrict__ wcoef,
    const u16* __restrict__ rcoef, const float* __restrict__ rw1arr,
    u16* __restrict__ readouts, float* __restrict__ out_tape) {
  const int bt = blockIdx.x;
  const int b = bt >> 1, t = bt & 1;
  const int tid = threadIdx.x;
  const int c = tid & 63;
  const int g = __builtin_amdgcn_readfirstlane(tid >> 6);
  __shared__ float lds_po[2][256];
  __shared__ float lds_pr[2][256];
  float tape[32];
#pragma unroll
  for (int j = 0; j < 32; ++j) tape[j] = 0.f;

  const unsigned* wcu = (const unsigned*)wcoef;
  const unsigned* rcu = (const unsigned*)rcoef;
  const size_t cbase = (size_t)bt * 64 + g * 16;
  const size_t vbase = (size_t)b * 128 + t * 64 + c;
  unsigned wA[16], rA[16], wB[16], rB[16];
  float rwA, rwB, vA, vB;
#pragma unroll
  for (int q = 0; q < 16; ++q) { wA[q] = wcu[cbase + q]; rA[q] = rcu[cbase + q]; }
  rwA = rw1arr[bt]; vA = values[vbase];
  {
    size_t nb = cbase + 8192;
#pragma unroll
    for (int q = 0; q < 16; ++q) { wB[q] = wcu[nb + q]; rB[q] = rcu[nb + q]; }
    rwB = rw1arr[128 + bt]; vB = values[8192 + vbase];
  }

#define BCF(u) __builtin_bit_cast(float, (u))
#define TSTEP(CW, CR, CRW, CV, S)                                              \
  {                                                                            \
    const int s_ = (S);                                                        \
    float rwc = CRW, vcl = CV;                                                 \
    float wsc[32], rsc[32];                                                    \
    _Pragma("unroll") for (int q = 0; q < 16; ++q) {                           \
      unsigned cw = (unsigned)__builtin_amdgcn_readfirstlane(CW[q]);           \
      unsigned cr = (unsigned)__builtin_amdgcn_readfirstlane(CR[q]);           \
      wsc[2 * q] = BCF(cw << 16);  wsc[2 * q + 1] = BCF(cw & 0xffff0000u);     \
      rsc[2 * q] = BCF(cr << 16);  rsc[2 * q + 1] = BCF(cr & 0xffff0000u);     \
    }                                                                          \
    float po_[4] = {0.f, 0.f, 0.f, 0.f};                                       \
    _Pragma("unroll") for (int j = 0; j < 32; ++j)                             \
      po_[j & 3] += tape[j] * wsc[j];                                          \
    if (s_ + 2 < 256) {                                                        \
      size_t nb = cbase + (size_t)(s_ + 2) * 8192;                             \
      _Pragma("unroll") for (int q = 0; q < 16; ++q) {                         \
        CW[q] = wcu[nb + q]; CR[q] = rcu[nb + q]; }                            \
      CRW = rw1arr[(s_ + 2) * 128 + bt];                                       \
      CV = values[(size_t)(s_ + 2) * 8192 + vbase];                            \
    }                                                                          \
    lds_po[s_ & 1][(g << 6) + c] = (po_[0] + po_[1]) + (po_[2] + po_[3]);      \
    __syncthreads();                                                           \
    if (g == 1 && s_ > 0) {                                                    \
      const float* pp = lds_pr[(s_ - 1) & 1];                                  \
      float ro = (pp[c] + pp[64 + c]) + (pp[128 + c] + pp[192 + c]);           \
      readouts[((size_t)(s_ - 1) * 64 + b) * 128 + t * 64 + c] = f2bf(ro);     \
    }                                                                          \
    const float* qq = lds_po[s_ & 1];                                          \
    float oldv = (qq[c] + qq[64 + c]) + (qq[128 + c] + qq[192 + c]);           \
    float dsc = rwc * (vcl - oldv);                                            \
    float pr_[4] = {0.f, 0.f, 0.f, 0.f};                                       \
    _Pragma("unroll") for (int j = 0; j < 32; ++j) {                           \
      tape[j] += wsc[j] * dsc;                                                 \
      pr_[j & 3] += tape[j] * rsc[j];                                          \
    }                                                                          \
    lds_pr[s_ & 1][(g << 6) + c] = (pr_[0] + pr_[1]) + (pr_[2] + pr_[3]);      \
  }

  for (int s = 0; s < 256; s += 2) {
    TSTEP(wA, rA, rwA, vA, s);
    TSTEP(wB, rB, rwB, vB, s + 1);
  }
#undef TSTEP
#undef BCF
  __syncthreads();
  if (g == 1) {
    const float* pp = lds_pr[1];
    float ro = (pp[c] + pp[64 + c]) + (pp[128 + c] + pp[192 + c]);
    readouts[((size_t)255 * 64 + b) * 128 + t * 64 + c] = f2bf(ro);
  }
#pragma unroll
  for (int j = 0; j < 32; ++j) {
    int l = (g << 5) + j;
    out_tape[((size_t)(l * 64 + b) * 2 + t) * 64 + c] = tape[j];
  }
}

// ---------------------------------------------------------------------------
extern "C" void kernel_launch(void* const* d_in, const int* in_sizes, int n_in,
                              void* d_out, int out_size, void* d_ws, size_t ws_size,
                              hipStream_t stream) {
  const float* inputs = (const float*)d_in[0];
  const float* W_ih_f = (const float*)d_in[2];
  const float* W_hh_f = (const float*)d_in[3];
  const float* b_ih_f = (const float*)d_in[4];
  const float* b_hh_f = (const float*)d_in[5];
  const float* W_ih_r = (const float*)d_in[6];
  const float* W_hh_r = (const float*)d_in[7];
  const float* b_ih_r = (const float*)d_in[8];
  const float* b_hh_r = (const float*)d_in[9];
  const float* W_act  = (const float*)d_in[10];
  const float* b_act  = (const float*)d_in[11];
  const float* W_val  = (const float*)d_in[12];
  const float* b_val  = (const float*)d_in[13];
  const float* W_out  = (const float*)d_in[14];
  const float* b_out  = (const float*)d_in[15];

  char* ws = (char*)d_ws;
  u16* in_bf    = (u16*)(ws + 0);
  u16* wihf_bf  = (u16*)(ws + 4194304);
  u16* whhf_bf  = (u16*)(ws + 4259840);
  u16* wihr_bf  = (u16*)(ws + 4292608);
  u16* whhr_bf  = (u16*)(ws + 4358144);
  u16* wval_bf  = (u16*)(ws + 4390912);
  u16* wout_bf  = (u16*)(ws + 4423680);
  u16* wact_bf  = (u16*)(ws + 4456448);
  float* xf       = (float*)(ws + 4460544);
  float* xr       = (float*)(ws + 21237760);
  float* values   = (float*)(ws + 38014976);
  u16* hidden_bf  = (u16*)(ws + 46403584);
  float* actraw   = (float*)(ws + 50597888);
  // overlays (xf/xr dead after k_lstm):
  u16* wcoef    = (u16*)(ws + 4460544);
  u16* rcoef    = (u16*)(ws + 12849152);
  float* rw1arr = (float*)(ws + 21237760);
  u16* readouts = (u16*)(ws + 21368832);       // ends 25563136 < 38014976 OK

  float* out_outputs = (float*)d_out;
  float* out_tape = out_outputs + 2097152;
  float* out_rpos = out_outputs + 3145728;
  float* out_wpos = out_outputs + 3162112;

  ConvArgs ca;
  ca.src[0] = inputs; ca.dst[0] = in_bf;
  ca.src[1] = W_ih_f; ca.dst[1] = wihf_bf;
  ca.src[2] = W_hh_f; ca.dst[2] = whhf_bf;
  ca.src[3] = W_ih_r; ca.dst[3] = wihr_bf;
  ca.src[4] = W_hh_r; ca.dst[4] = whhr_bf;
  ca.src[5] = W_val;  ca.dst[5] = wval_bf;
  ca.src[6] = W_out;  ca.dst[6] = wout_bf;
  ca.src[7] = W_act;  ca.dst[7] = wact_bf;
  const int offs[9] = {0, 2097152, 2129920, 2146304, 2179072, 2195456,
                       2211840, 2228224, 2230272};
  for (int i = 0; i < 9; ++i) ca.off[i] = offs[i];

  hipLaunchKernelGGL(k_convert, dim3(2568), dim3(256), 0, stream, ca);
  hipLaunchKernelGGL(k_gemm_in, dim3(10240), dim3(256), 0, stream,
                     in_bf, wihf_bf, wihr_bf, wval_bf,
                     b_ih_f, b_hh_f, b_ih_r, b_hh_r, b_val, xf, xr, values);
  hipLaunchKernelGGL(k_lstm, dim3(8), dim3(256), 0, stream,
                     whhf_bf, whhr_bf, xf, xr, hidden_bf);
  hipLaunchKernelGGL(k_gemm_act, dim3(512), dim3(256), 0, stream,
                     hidden_bf, wact_bf, b_act, actraw);
  hipLaunchKernelGGL(k_pos, dim3(128), dim3(64), 0, stream,
                     actraw, wcoef, rcoef, rw1arr, out_rpos, out_wpos);
  hipLaunchKernelGGL(k_tape2, dim3(128), dim3(256), 0, stream,
                     values, wcoef, rcoef, rw1arr, readouts, out_tape);
  hipLaunchKernelGGL(k_gemm_out, dim3(2048), dim3(256), 0, stream,
                     readouts, wout_bf, b_out, out_outputs);
}